// Round 1
// baseline (812.402 us; speedup 1.0000x reference)
//
#include <hip/hip_runtime.h>
#include <hip/hip_bf16.h>
#include <cstdint>
#include <cstddef>

static constexpr int T_TOK = 8192;   // B*S
static constexpr int D_DIM = 768;
static constexpr int E_NUM = 8;
static constexpr int F_DIM = 3072;

typedef __attribute__((ext_vector_type(8))) short short8;
typedef __attribute__((ext_vector_type(4))) float floatx4;

__device__ __forceinline__ void async16(const void* g, void* l) {
  __builtin_amdgcn_global_load_lds(
      (const __attribute__((address_space(1))) unsigned int*)g,
      (__attribute__((address_space(3))) unsigned int*)l, 16, 0, 0);
}

__device__ __forceinline__ float gelu_exact(float v) {
  return 0.5f * v * (1.0f + erff(v * 0.70710678118654752f));
}

// ---------------- gate: logits fp32, argmax, fused x->bf16 ----------------
__global__ __launch_bounds__(256)
void gate_kernel(const float* __restrict__ x, const float* __restrict__ gw,
                 const float* __restrict__ gb, int* __restrict__ expert_idx,
                 int* __restrict__ counts, __hip_bfloat16* __restrict__ xb) {
  int gid = blockIdx.x * blockDim.x + threadIdx.x;
  int tok = gid >> 6;
  int lane = threadIdx.x & 63;
  if (tok >= T_TOK) return;
  const float* xr = x + (size_t)tok * D_DIM;
  __hip_bfloat16* xbr = xb + (size_t)tok * D_DIM;
  float acc[8];
#pragma unroll
  for (int e = 0; e < 8; e++) acc[e] = 0.f;
#pragma unroll
  for (int i = 0; i < D_DIM / 64; i++) {
    int d = lane + i * 64;
    float v = xr[d];
    xbr[d] = __float2bfloat16(v);
    const float4* g4 = (const float4*)(gw + (size_t)d * 8);
    float4 a = g4[0], b = g4[1];
    acc[0] += v * a.x; acc[1] += v * a.y; acc[2] += v * a.z; acc[3] += v * a.w;
    acc[4] += v * b.x; acc[5] += v * b.y; acc[6] += v * b.z; acc[7] += v * b.w;
  }
#pragma unroll
  for (int e = 0; e < 8; e++) {
#pragma unroll
    for (int o = 32; o > 0; o >>= 1) acc[e] += __shfl_xor(acc[e], o, 64);
  }
  if (lane == 0) {
    int best = 0;
    float bv = acc[0] + gb[0];
#pragma unroll
    for (int e = 1; e < 8; e++) {
      float v = acc[e] + gb[e];
      if (v > bv) { bv = v; best = e; }  // strict > keeps lowest index on ties (np.argmax)
    }
    expert_idx[tok] = best;
    atomicAdd(&counts[best], 1);
  }
}

// ---------------- tiny prefix sum over 8 experts ----------------
__global__ void offsets_kernel(const int* __restrict__ counts, int* __restrict__ offs) {
  if (threadIdx.x == 0) {
    int s = 0;
    for (int e = 0; e < E_NUM; e++) { offs[e] = s; s += counts[e]; }
    offs[E_NUM] = s;
  }
}

// ---------------- bucket tokens by expert ----------------
__global__ __launch_bounds__(256)
void scatter_kernel(const int* __restrict__ expert_idx, const int* __restrict__ offs,
                    int* __restrict__ fill, int* __restrict__ perm) {
  int t = blockIdx.x * blockDim.x + threadIdx.x;
  if (t >= T_TOK) return;
  int e = expert_idx[t];
  int pos = offs[e] + atomicAdd(&fill[e], 1);
  perm[pos] = t;
}

// ---------------- weight transpose + fp32->bf16: in [R][C] -> out [C][R] ----------------
__global__ __launch_bounds__(256)
void transpose_bf16(const float* __restrict__ in, __hip_bfloat16* __restrict__ out,
                    int R, int C) {
  __shared__ float tile[32][33];
  const float* src = in + (size_t)blockIdx.z * R * C;
  __hip_bfloat16* dst = out + (size_t)blockIdx.z * R * C;
  int tx = threadIdx.x & 31, ty = threadIdx.x >> 5;
  int r0 = blockIdx.y * 32, c0 = blockIdx.x * 32;
#pragma unroll
  for (int i = 0; i < 4; i++)
    tile[ty + i * 8][tx] = src[(size_t)(r0 + ty + i * 8) * C + c0 + tx];
  __syncthreads();
#pragma unroll
  for (int i = 0; i < 4; i++)
    dst[(size_t)(c0 + ty + i * 8) * R + r0 + tx] = __float2bfloat16(tile[tx][ty + i * 8]);
}

// ---------------- grouped GEMM: C[M,N] = A[M,K] @ Bt[N,K]^T, 128x128x32 tiles ----------------
// IS_FFN1: A rows gathered via perm (xb), epilogue gelu(.+b1) -> H (bf16, permuted rows)
// else:    A rows contiguous (H),        epilogue (.+b2) scattered to Out via perm
template <int N, int K, bool IS_FFN1>
__global__ __launch_bounds__(256)
void moe_gemm(const __hip_bfloat16* __restrict__ A,
              const __hip_bfloat16* __restrict__ Bt,
              const float* __restrict__ bias,
              const int* __restrict__ offs,
              const int* __restrict__ perm,
              __hip_bfloat16* __restrict__ Hout,
              float* __restrict__ Out) {
  int e = blockIdx.x >> 6;
  int mt = blockIdx.x & 63;
  int off = offs[e];
  int cnt = offs[e + 1] - off;
  int m0 = mt * 128;
  if (m0 >= cnt) return;
  int n0 = blockIdx.y * 128;

  __shared__ __align__(16) __hip_bfloat16 As[128 * 32];  // [m][k]
  __shared__ __align__(16) __hip_bfloat16 Bs[128 * 32];  // [n][k]

  int tid = threadIdx.x;
  int lane = tid & 63;
  int w = tid >> 6;

  // staging: wave w covers rows [w*32, w*32+32); lane -> row w*32 + i*16 + (lane>>2), 16B chunk lane&3
  int lr0 = w * 32 + (lane >> 2);
  int lr1 = lr0 + 16;
  int ch = lane & 3;

  int r0 = m0 + lr0; if (r0 > cnt - 1) r0 = cnt - 1;  // clamp: masked at C-write
  int r1 = m0 + lr1; if (r1 > cnt - 1) r1 = cnt - 1;
  size_t arow0, arow1;
  if constexpr (IS_FFN1) {
    arow0 = (size_t)perm[off + r0] * K;
    arow1 = (size_t)perm[off + r1] * K;
  } else {
    arow0 = (size_t)(off + r0) * K;
    arow1 = (size_t)(off + r1) * K;
  }
  const __hip_bfloat16* Bbase = Bt + ((size_t)e * N + n0) * K;
  size_t brow0 = (size_t)lr0 * K;
  size_t brow1 = (size_t)lr1 * K;

  floatx4 acc[4][4];
#pragma unroll
  for (int i = 0; i < 4; i++)
#pragma unroll
    for (int j = 0; j < 4; j++) acc[i][j] = (floatx4){0.f, 0.f, 0.f, 0.f};

  int wr = (w >> 1) * 64, wc = (w & 1) * 64;  // wave's 64x64 quadrant
  int mrow = lane & 15;
  int kq = (lane >> 4) * 8;

  for (int kk = 0; kk < K; kk += 32) {
    __syncthreads();  // previous iter's ds_reads done before overwrite
    async16(A + arow0 + kk + ch * 8, &As[(w * 32) * 32]);
    async16(A + arow1 + kk + ch * 8, &As[(w * 32 + 16) * 32]);
    async16(Bbase + brow0 + kk + ch * 8, &Bs[(w * 32) * 32]);
    async16(Bbase + brow1 + kk + ch * 8, &Bs[(w * 32 + 16) * 32]);
    __syncthreads();  // compiler drains vmcnt before s_barrier

    short8 af[4], bf[4];
#pragma unroll
    for (int i = 0; i < 4; i++)
      af[i] = *(const short8*)&As[(wr + i * 16 + mrow) * 32 + kq];
#pragma unroll
    for (int i = 0; i < 4; i++)
      bf[i] = *(const short8*)&Bs[(wc + i * 16 + mrow) * 32 + kq];
#pragma unroll
    for (int mi = 0; mi < 4; mi++)
#pragma unroll
      for (int ni = 0; ni < 4; ni++)
        acc[mi][ni] = __builtin_amdgcn_mfma_f32_16x16x32_bf16(af[mi], bf[ni], acc[mi][ni], 0, 0, 0);
  }

  // epilogue: C/D layout col=lane&15, row=(lane>>4)*4+reg [m89]
#pragma unroll
  for (int mi = 0; mi < 4; mi++) {
    int rowl = wr + mi * 16 + (lane >> 4) * 4;
#pragma unroll
    for (int ni = 0; ni < 4; ni++) {
      int col = n0 + wc + ni * 16 + (lane & 15);
      float bia = bias[(size_t)e * N + col];
#pragma unroll
      for (int r = 0; r < 4; r++) {
        int gm = m0 + rowl + r;
        if (gm < cnt) {
          float v = acc[mi][ni][r] + bia;
          if constexpr (IS_FFN1) {
            Hout[(size_t)(off + gm) * N + col] = __float2bfloat16(gelu_exact(v));
          } else {
            Out[(size_t)perm[off + gm] * N + col] = v;
          }
        }
      }
    }
  }
}

extern "C" void kernel_launch(void* const* d_in, const int* in_sizes, int n_in,
                              void* d_out, int out_size, void* d_ws, size_t ws_size,
                              hipStream_t stream) {
  const float* x  = (const float*)d_in[0];
  const float* gw = (const float*)d_in[1];
  const float* gb = (const float*)d_in[2];
  const float* w1 = (const float*)d_in[3];
  const float* b1 = (const float*)d_in[4];
  const float* w2 = (const float*)d_in[5];
  const float* b2 = (const float*)d_in[6];
  float* out = (float*)d_out;

  char* ws = (char*)d_ws;
  int* counts = (int*)(ws + 0);    // 8 ints
  int* fill   = (int*)(ws + 32);   // 8 ints
  int* offs   = (int*)(ws + 64);   // 9 ints
  int* eidx   = (int*)(ws + 256);
  int* perm   = (int*)(ws + 256 + 4 * T_TOK);
  size_t off = 256 + 8 * (size_t)T_TOK;
  __hip_bfloat16* xb  = (__hip_bfloat16*)(ws + off); off += (size_t)T_TOK * D_DIM * 2;
  __hip_bfloat16* w1t = (__hip_bfloat16*)(ws + off); off += (size_t)E_NUM * D_DIM * F_DIM * 2;
  __hip_bfloat16* w2t = (__hip_bfloat16*)(ws + off); off += (size_t)E_NUM * D_DIM * F_DIM * 2;
  __hip_bfloat16* H   = (__hip_bfloat16*)(ws + off); off += (size_t)T_TOK * F_DIM * 2;

  hipMemsetAsync(d_ws, 0, 64, stream);  // counts + fill
  gate_kernel<<<T_TOK / 4, 256, 0, stream>>>(x, gw, gb, eidx, counts, xb);
  offsets_kernel<<<1, 64, 0, stream>>>(counts, offs);
  scatter_kernel<<<T_TOK / 256, 256, 0, stream>>>(eidx, offs, fill, perm);
  // w1 [E][D][F] -> w1t [E][F][D] ;  w2 [E][F][D] -> w2t [E][D][F]
  transpose_bf16<<<dim3(F_DIM / 32, D_DIM / 32, E_NUM), 256, 0, stream>>>(w1, w1t, D_DIM, F_DIM);
  transpose_bf16<<<dim3(D_DIM / 32, F_DIM / 32, E_NUM), 256, 0, stream>>>(w2, w2t, F_DIM, D_DIM);
  moe_gemm<F_DIM, D_DIM, true><<<dim3(E_NUM * 64, F_DIM / 128), 256, 0, stream>>>(
      xb, w1t, b1, offs, perm, H, nullptr);
  moe_gemm<D_DIM, F_DIM, false><<<dim3(E_NUM * 64, D_DIM / 128), 256, 0, stream>>>(
      H, w2t, b2, offs, perm, nullptr, out);
}

// Round 2
// 536.857 us; speedup vs baseline: 1.5133x; 1.5133x over previous
//
#include <hip/hip_runtime.h>
#include <hip/hip_bf16.h>
#include <cstdint>
#include <cstddef>

static constexpr int T_TOK = 8192;   // B*S
static constexpr int D_DIM = 768;
static constexpr int E_NUM = 8;
static constexpr int F_DIM = 3072;
static constexpr int MAX_TILES = 72; // sum_e ceil(cnt_e/128) <= 64 + 7

typedef __attribute__((ext_vector_type(8))) short short8;
typedef __attribute__((ext_vector_type(4))) float floatx4;
typedef __attribute__((ext_vector_type(8))) unsigned short ushort8v;

__device__ __forceinline__ void async16(const void* g, void* l) {
  __builtin_amdgcn_global_load_lds(
      (const __attribute__((address_space(1))) unsigned int*)g,
      (__attribute__((address_space(3))) unsigned int*)l, 16, 0, 0);
}

__device__ __forceinline__ float gelu_exact(float v) {
  return 0.5f * v * (1.0f + erff(v * 0.70710678118654752f));
}

// ---------------- gate: logits fp32, argmax, fused x->bf16 ----------------
__global__ __launch_bounds__(256)
void gate_kernel(const float* __restrict__ x, const float* __restrict__ gw,
                 const float* __restrict__ gb, int* __restrict__ expert_idx,
                 int* __restrict__ counts, __hip_bfloat16* __restrict__ xb) {
  int gid = blockIdx.x * blockDim.x + threadIdx.x;
  int tok = gid >> 6;
  int lane = threadIdx.x & 63;
  if (tok >= T_TOK) return;
  const float* xr = x + (size_t)tok * D_DIM;
  __hip_bfloat16* xbr = xb + (size_t)tok * D_DIM;
  float acc[8];
#pragma unroll
  for (int e = 0; e < 8; e++) acc[e] = 0.f;
#pragma unroll
  for (int i = 0; i < D_DIM / 64; i++) {
    int d = lane + i * 64;
    float v = xr[d];
    xbr[d] = __float2bfloat16(v);
    const float4* g4 = (const float4*)(gw + (size_t)d * 8);
    float4 a = g4[0], b = g4[1];
    acc[0] += v * a.x; acc[1] += v * a.y; acc[2] += v * a.z; acc[3] += v * a.w;
    acc[4] += v * b.x; acc[5] += v * b.y; acc[6] += v * b.z; acc[7] += v * b.w;
  }
#pragma unroll
  for (int e = 0; e < 8; e++) {
#pragma unroll
    for (int o = 32; o > 0; o >>= 1) acc[e] += __shfl_xor(acc[e], o, 64);
  }
  if (lane == 0) {
    int best = 0;
    float bv = acc[0] + gb[0];
#pragma unroll
    for (int e = 1; e < 8; e++) {
      float v = acc[e] + gb[e];
      if (v > bv) { bv = v; best = e; }  // strict > == np.argmax tie-break
    }
    expert_idx[tok] = best;
    atomicAdd(&counts[best], 1);
  }
}

// ---------------- offsets + compact tile table ----------------
// meta[0] = n_tiles; meta[1..72] = expert id; meta[73..144] = m-tile idx
__global__ void offsets_kernel(const int* __restrict__ counts, int* __restrict__ offs,
                               int* __restrict__ meta) {
  if (threadIdx.x == 0) {
    int s = 0, tc = 0;
    for (int e = 0; e < E_NUM; e++) {
      offs[e] = s;
      int cnt = counts[e];
      for (int m = 0; m * 128 < cnt; m++) {
        meta[1 + tc] = e;
        meta[1 + MAX_TILES + tc] = m;
        tc++;
      }
      s += cnt;
    }
    offs[E_NUM] = s;
    meta[0] = tc;
  }
}

// ---------------- bucket tokens by expert ----------------
__global__ __launch_bounds__(256)
void scatter_kernel(const int* __restrict__ expert_idx, const int* __restrict__ offs,
                    int* __restrict__ fill, int* __restrict__ perm) {
  int t = blockIdx.x * blockDim.x + threadIdx.x;
  if (t >= T_TOK) return;
  int e = expert_idx[t];
  int pos = offs[e] + atomicAdd(&fill[e], 1);
  perm[pos] = t;
}

// ---------------- weight transpose + cast: in [R][C] fp32 -> out [C][R] bf16 ----
// 64x64 tiles, 16B vector writes
__global__ __launch_bounds__(256)
void transpose_bf16(const float* __restrict__ in, __hip_bfloat16* __restrict__ out,
                    int R, int C) {
  __shared__ float t[64][65];
  const float* src = in + (size_t)blockIdx.z * R * C;
  __hip_bfloat16* dst = out + (size_t)blockIdx.z * R * C;
  int r0 = blockIdx.y * 64, c0 = blockIdx.x * 64;
  int tx = threadIdx.x & 15;   // 16 lanes x float4 = 64 cols
  int ty = threadIdx.x >> 4;   // 16 rows per pass
#pragma unroll
  for (int p = 0; p < 4; p++) {
    int r = ty + p * 16;
    float4 v = *(const float4*)&src[(size_t)(r0 + r) * C + c0 + tx * 4];
    t[tx * 4 + 0][r] = v.x; t[tx * 4 + 1][r] = v.y;
    t[tx * 4 + 2][r] = v.z; t[tx * 4 + 3][r] = v.w;
  }
  __syncthreads();
  int j = threadIdx.x & 7;     // 8 lanes x 8 bf16 (16B) = 64-elem row
#pragma unroll
  for (int p = 0; p < 2; p++) {
    int cc = (threadIdx.x >> 3) + p * 32;
    __align__(16) __hip_bfloat16 tmp[8];
#pragma unroll
    for (int i = 0; i < 8; i++) tmp[i] = __float2bfloat16(t[cc][j * 8 + i]);
    *(ushort8v*)&dst[(size_t)(c0 + cc) * R + r0 + j * 8] = *(const ushort8v*)tmp;
  }
}

// ---------------- GEMM1: H[perm-order] = gelu(xb_gathered @ w1t^T + b1) ----------
// 128x128x32 tiles, compacted m-tile grid, XOR-swizzled LDS (2-way = free)
__global__ __launch_bounds__(256)
void moe_gemm1(const __hip_bfloat16* __restrict__ A,   // xb [T][D]
               const __hip_bfloat16* __restrict__ Bt,  // w1t [E][F][D]
               const float* __restrict__ bias,         // b1 [E][F]
               const int* __restrict__ meta,
               const int* __restrict__ offs,
               const int* __restrict__ perm,
               __hip_bfloat16* __restrict__ H) {
  constexpr int K = D_DIM, N = F_DIM;
  int bx = blockIdx.x;
  if (bx >= meta[0]) return;
  int e = meta[1 + bx];
  int m0 = meta[1 + MAX_TILES + bx] * 128;
  int off = offs[e], cnt = offs[e + 1] - off;
  int n0 = blockIdx.y * 128;

  __shared__ __align__(16) __hip_bfloat16 As[128 * 32];
  __shared__ __align__(16) __hip_bfloat16 Bs[128 * 32];

  int tid = threadIdx.x, lane = tid & 63, w = tid >> 6;
  int lr0 = w * 32 + (lane >> 2), lr1 = lr0 + 16;
  int ch = (lane & 3) ^ ((lane >> 3) & 3);  // XOR-swizzled source chunk

  int r0 = m0 + lr0; if (r0 > cnt - 1) r0 = cnt - 1;
  int r1 = m0 + lr1; if (r1 > cnt - 1) r1 = cnt - 1;
  const __hip_bfloat16* a0 = A + (size_t)perm[off + r0] * K + ch * 8;
  const __hip_bfloat16* a1 = A + (size_t)perm[off + r1] * K + ch * 8;
  const __hip_bfloat16* Bbase = Bt + ((size_t)e * N + n0) * K;
  const __hip_bfloat16* bp0 = Bbase + (size_t)lr0 * K + ch * 8;
  const __hip_bfloat16* bp1 = Bbase + (size_t)lr1 * K + ch * 8;

  int wr = (w >> 1) * 64, wc = (w & 1) * 64;
  int mrow = lane & 15, cq = lane >> 4;
  int aoff[4], boff[4];
#pragma unroll
  for (int i = 0; i < 4; i++) {
    int rr = wr + i * 16 + mrow;
    aoff[i] = rr * 32 + ((cq ^ ((rr >> 1) & 3)) * 8);
    int rb = wc + i * 16 + mrow;
    boff[i] = rb * 32 + ((cq ^ ((rb >> 1) & 3)) * 8);
  }

  floatx4 acc[4][4];
#pragma unroll
  for (int i = 0; i < 4; i++)
#pragma unroll
    for (int j = 0; j < 4; j++) acc[i][j] = (floatx4){0.f, 0.f, 0.f, 0.f};

  for (int kk = 0; kk < K; kk += 32) {
    __syncthreads();
    async16(a0 + kk, &As[(w * 32) * 32]);
    async16(a1 + kk, &As[(w * 32 + 16) * 32]);
    async16(bp0 + kk, &Bs[(w * 32) * 32]);
    async16(bp1 + kk, &Bs[(w * 32 + 16) * 32]);
    __syncthreads();
    short8 af[4], bf[4];
#pragma unroll
    for (int i = 0; i < 4; i++) af[i] = *(const short8*)&As[aoff[i]];
#pragma unroll
    for (int i = 0; i < 4; i++) bf[i] = *(const short8*)&Bs[boff[i]];
#pragma unroll
    for (int mi = 0; mi < 4; mi++)
#pragma unroll
      for (int ni = 0; ni < 4; ni++)
        acc[mi][ni] = __builtin_amdgcn_mfma_f32_16x16x32_bf16(af[mi], bf[ni], acc[mi][ni], 0, 0, 0);
  }

#pragma unroll
  for (int mi = 0; mi < 4; mi++) {
    int rowl = wr + mi * 16 + (lane >> 4) * 4;
#pragma unroll
    for (int ni = 0; ni < 4; ni++) {
      int col = n0 + wc + ni * 16 + (lane & 15);
      float bia = bias[(size_t)e * N + col];
#pragma unroll
      for (int r = 0; r < 4; r++) {
        int gm = m0 + rowl + r;
        if (gm < cnt)
          H[(size_t)(off + gm) * N + col] = __float2bfloat16(gelu_exact(acc[mi][ni][r] + bia));
      }
    }
  }
}

// ---------------- GEMM2: out[perm] = H @ w2t^T + b2, 128x64x32 tiles ----------
__global__ __launch_bounds__(256)
void moe_gemm2(const __hip_bfloat16* __restrict__ A,   // H [T][F] (permuted rows)
               const __hip_bfloat16* __restrict__ Bt,  // w2t [E][D][F]
               const float* __restrict__ bias,         // b2 [E][D]
               const int* __restrict__ meta,
               const int* __restrict__ offs,
               const int* __restrict__ perm,
               float* __restrict__ Out) {
  constexpr int K = F_DIM, N = D_DIM;
  int bx = blockIdx.x;
  if (bx >= meta[0]) return;
  int e = meta[1 + bx];
  int m0 = meta[1 + MAX_TILES + bx] * 128;
  int off = offs[e], cnt = offs[e + 1] - off;
  int n0 = blockIdx.y * 64;

  __shared__ __align__(16) __hip_bfloat16 As[128 * 32];
  __shared__ __align__(16) __hip_bfloat16 Bs[64 * 32];

  int tid = threadIdx.x, lane = tid & 63, w = tid >> 6;
  int lr0 = w * 32 + (lane >> 2), lr1 = lr0 + 16;
  int ch = (lane & 3) ^ ((lane >> 3) & 3);

  int r0 = m0 + lr0; if (r0 > cnt - 1) r0 = cnt - 1;
  int r1 = m0 + lr1; if (r1 > cnt - 1) r1 = cnt - 1;
  const __hip_bfloat16* a0 = A + (size_t)(off + r0) * K + ch * 8;
  const __hip_bfloat16* a1 = A + (size_t)(off + r1) * K + ch * 8;
  int br = w * 16 + (lane >> 2);  // wave w stages Bs rows [w*16, w*16+16)
  const __hip_bfloat16* bp0 = Bt + ((size_t)e * N + n0 + br) * K + ch * 8;

  int mrow = lane & 15, cq = lane >> 4;
  int aoff[2], boff[4];
#pragma unroll
  for (int i = 0; i < 2; i++) {
    int rr = w * 32 + i * 16 + mrow;
    aoff[i] = rr * 32 + ((cq ^ ((rr >> 1) & 3)) * 8);
  }
#pragma unroll
  for (int i = 0; i < 4; i++) {
    int rb = i * 16 + mrow;
    boff[i] = rb * 32 + ((cq ^ ((rb >> 1) & 3)) * 8);
  }

  floatx4 acc[2][4];
#pragma unroll
  for (int i = 0; i < 2; i++)
#pragma unroll
    for (int j = 0; j < 4; j++) acc[i][j] = (floatx4){0.f, 0.f, 0.f, 0.f};

  for (int kk = 0; kk < K; kk += 32) {
    __syncthreads();
    async16(a0 + kk, &As[(w * 32) * 32]);
    async16(a1 + kk, &As[(w * 32 + 16) * 32]);
    async16(bp0 + kk, &Bs[(w * 16) * 32]);
    __syncthreads();
    short8 af[2], bf[4];
#pragma unroll
    for (int i = 0; i < 2; i++) af[i] = *(const short8*)&As[aoff[i]];
#pragma unroll
    for (int i = 0; i < 4; i++) bf[i] = *(const short8*)&Bs[boff[i]];
#pragma unroll
    for (int mi = 0; mi < 2; mi++)
#pragma unroll
      for (int ni = 0; ni < 4; ni++)
        acc[mi][ni] = __builtin_amdgcn_mfma_f32_16x16x32_bf16(af[mi], bf[ni], acc[mi][ni], 0, 0, 0);
  }

#pragma unroll
  for (int mi = 0; mi < 2; mi++) {
    int rowl = w * 32 + mi * 16 + (lane >> 4) * 4;
#pragma unroll
    for (int ni = 0; ni < 4; ni++) {
      int col = n0 + ni * 16 + (lane & 15);
      float bia = bias[(size_t)e * N + col];
#pragma unroll
      for (int r = 0; r < 4; r++) {
        int gm = m0 + rowl + r;
        if (gm < cnt)
          Out[(size_t)perm[off + gm] * N + col] = acc[mi][ni][r] + bia;
      }
    }
  }
}

extern "C" void kernel_launch(void* const* d_in, const int* in_sizes, int n_in,
                              void* d_out, int out_size, void* d_ws, size_t ws_size,
                              hipStream_t stream) {
  const float* x  = (const float*)d_in[0];
  const float* gw = (const float*)d_in[1];
  const float* gb = (const float*)d_in[2];
  const float* w1 = (const float*)d_in[3];
  const float* b1 = (const float*)d_in[4];
  const float* w2 = (const float*)d_in[5];
  const float* b2 = (const float*)d_in[6];
  float* out = (float*)d_out;

  char* ws = (char*)d_ws;
  int* counts = (int*)(ws + 0);     // 8
  int* fill   = (int*)(ws + 32);    // 8
  int* offs   = (int*)(ws + 64);    // 9
  int* meta   = (int*)(ws + 128);   // 1 + 72 + 72 = 145 ints (580 B)
  int* eidx   = (int*)(ws + 1024);
  int* perm   = (int*)(ws + 1024 + 4 * T_TOK);
  size_t off = 1024 + 8 * (size_t)T_TOK;
  __hip_bfloat16* xb  = (__hip_bfloat16*)(ws + off); off += (size_t)T_TOK * D_DIM * 2;
  __hip_bfloat16* w1t = (__hip_bfloat16*)(ws + off); off += (size_t)E_NUM * D_DIM * F_DIM * 2;
  __hip_bfloat16* w2t = (__hip_bfloat16*)(ws + off); off += (size_t)E_NUM * D_DIM * F_DIM * 2;
  __hip_bfloat16* H   = (__hip_bfloat16*)(ws + off); off += (size_t)T_TOK * F_DIM * 2;

  hipMemsetAsync(d_ws, 0, 64, stream);  // counts + fill
  gate_kernel<<<T_TOK / 4, 256, 0, stream>>>(x, gw, gb, eidx, counts, xb);
  offsets_kernel<<<1, 64, 0, stream>>>(counts, offs, meta);
  scatter_kernel<<<T_TOK / 256, 256, 0, stream>>>(eidx, offs, fill, perm);
  // w1 [E][768][3072] -> w1t [E][3072][768] ; w2 [E][3072][768] -> w2t [E][768][3072]
  transpose_bf16<<<dim3(F_DIM / 64, D_DIM / 64, E_NUM), 256, 0, stream>>>(w1, w1t, D_DIM, F_DIM);
  transpose_bf16<<<dim3(D_DIM / 64, F_DIM / 64, E_NUM), 256, 0, stream>>>(w2, w2t, F_DIM, D_DIM);
  moe_gemm1<<<dim3(MAX_TILES, F_DIM / 128), 256, 0, stream>>>(xb, w1t, b1, meta, offs, perm, H);
  moe_gemm2<<<dim3(MAX_TILES, D_DIM / 64), 256, 0, stream>>>(H, w2t, b2, meta, offs, perm, out);
}

// Round 3
// 506.278 us; speedup vs baseline: 1.6047x; 1.0604x over previous
//
#include <hip/hip_runtime.h>
#include <hip/hip_bf16.h>
#include <cstdint>
#include <cstddef>

static constexpr int T_TOK = 8192;   // B*S
static constexpr int D_DIM = 768;
static constexpr int E_NUM = 8;
static constexpr int F_DIM = 3072;
static constexpr int MAX_TILES = 72; // 8 XCD groups x 9 m-tiles; sum ceil(cnt/128) <= 71

typedef __attribute__((ext_vector_type(8))) short short8;
typedef __attribute__((ext_vector_type(4))) float floatx4;
typedef __attribute__((ext_vector_type(8))) unsigned short ushort8v;

__device__ __forceinline__ void async16(const void* g, void* l) {
  __builtin_amdgcn_global_load_lds(
      (const __attribute__((address_space(1))) unsigned int*)g,
      (__attribute__((address_space(3))) unsigned int*)l, 16, 0, 0);
}

// gelu tanh-approx in sigmoid form: x*sigmoid(1.59577x + 0.0713548x^3)
// max dev vs exact erf-gelu ~3e-4 (we have 4.8x absmax headroom)
__device__ __forceinline__ float gelu_fast(float v) {
  float s = v * (1.5957691f + 0.071354813f * v * v);
  return v / (1.0f + __expf(-s));
}

// ---------------- gate: logits fp32, argmax, fused x->bf16 ----------------
__global__ __launch_bounds__(256)
void gate_kernel(const float* __restrict__ x, const float* __restrict__ gw,
                 const float* __restrict__ gb, int* __restrict__ expert_idx,
                 int* __restrict__ counts, __hip_bfloat16* __restrict__ xb) {
  int gid = blockIdx.x * blockDim.x + threadIdx.x;
  int tok = gid >> 6;
  int lane = threadIdx.x & 63;
  if (tok >= T_TOK) return;
  const float* xr = x + (size_t)tok * D_DIM;
  __hip_bfloat16* xbr = xb + (size_t)tok * D_DIM;
  float acc[8];
#pragma unroll
  for (int e = 0; e < 8; e++) acc[e] = 0.f;
#pragma unroll
  for (int i = 0; i < D_DIM / 64; i++) {
    int d = lane + i * 64;
    float v = xr[d];
    xbr[d] = __float2bfloat16(v);
    const float4* g4 = (const float4*)(gw + (size_t)d * 8);
    float4 a = g4[0], b = g4[1];
    acc[0] += v * a.x; acc[1] += v * a.y; acc[2] += v * a.z; acc[3] += v * a.w;
    acc[4] += v * b.x; acc[5] += v * b.y; acc[6] += v * b.z; acc[7] += v * b.w;
  }
#pragma unroll
  for (int e = 0; e < 8; e++) {
#pragma unroll
    for (int o = 32; o > 0; o >>= 1) acc[e] += __shfl_xor(acc[e], o, 64);
  }
  if (lane == 0) {
    int best = 0;
    float bv = acc[0] + gb[0];
#pragma unroll
    for (int e = 1; e < 8; e++) {
      float v = acc[e] + gb[e];
      if (v > bv) { bv = v; best = e; }  // strict > == np.argmax tie-break
    }
    expert_idx[tok] = best;
    atomicAdd(&counts[best], 1);
  }
}

// ---------------- offsets + compact tile table ----------------
__global__ void offsets_kernel(const int* __restrict__ counts, int* __restrict__ offs,
                               int* __restrict__ meta) {
  if (threadIdx.x == 0) {
    int s = 0, tc = 0;
    for (int e = 0; e < E_NUM; e++) {
      offs[e] = s;
      int cnt = counts[e];
      for (int m = 0; m * 128 < cnt; m++) {
        meta[1 + tc] = e;
        meta[1 + MAX_TILES + tc] = m;
        tc++;
      }
      s += cnt;
    }
    offs[E_NUM] = s;
    meta[0] = tc;
  }
}

// ---------------- bucket tokens by expert ----------------
__global__ __launch_bounds__(256)
void scatter_kernel(const int* __restrict__ expert_idx, const int* __restrict__ offs,
                    int* __restrict__ fill, int* __restrict__ perm) {
  int t = blockIdx.x * blockDim.x + threadIdx.x;
  if (t >= T_TOK) return;
  int e = expert_idx[t];
  int pos = offs[e] + atomicAdd(&fill[e], 1);
  perm[pos] = t;
}

// ---------------- weight transpose + cast: in [R][C] fp32 -> out [C][R] bf16 ----
__global__ __launch_bounds__(256)
void transpose_bf16(const float* __restrict__ in, __hip_bfloat16* __restrict__ out,
                    int R, int C) {
  __shared__ float t[64][65];
  const float* src = in + (size_t)blockIdx.z * R * C;
  __hip_bfloat16* dst = out + (size_t)blockIdx.z * R * C;
  int r0 = blockIdx.y * 64, c0 = blockIdx.x * 64;
  int tx = threadIdx.x & 15;
  int ty = threadIdx.x >> 4;
#pragma unroll
  for (int p = 0; p < 4; p++) {
    int r = ty + p * 16;
    float4 v = *(const float4*)&src[(size_t)(r0 + r) * C + c0 + tx * 4];
    t[tx * 4 + 0][r] = v.x; t[tx * 4 + 1][r] = v.y;
    t[tx * 4 + 2][r] = v.z; t[tx * 4 + 3][r] = v.w;
  }
  __syncthreads();
  int j = threadIdx.x & 7;
#pragma unroll
  for (int p = 0; p < 2; p++) {
    int cc = (threadIdx.x >> 3) + p * 32;
    __align__(16) __hip_bfloat16 tmp[8];
#pragma unroll
    for (int i = 0; i < 8; i++) tmp[i] = __float2bfloat16(t[cc][j * 8 + i]);
    *(ushort8v*)&dst[(size_t)(c0 + cc) * R + r0 + j * 8] = *(const ushort8v*)tmp;
  }
}

// ---------------- GEMM1: H[perm-order] = gelu(xb_gathered @ w1t^T + b1) ----------
// 128x128 tile, BK=64 as two swizzled BK=32 sub-tiles per barrier pair.
// Grid: 8 XCD groups x (9 m-tiles x 24 n-tiles); xcd = blockIdx.x & 7 keeps a
// B-slab resident in one XCD's L2.
__global__ __launch_bounds__(256)
void moe_gemm1(const __hip_bfloat16* __restrict__ A,   // xb [T][D]
               const __hip_bfloat16* __restrict__ Bt,  // w1t [E][F][D]
               const float* __restrict__ bias,         // b1 [E][F]
               const int* __restrict__ meta,
               const int* __restrict__ offs,
               const int* __restrict__ perm,
               __hip_bfloat16* __restrict__ H) {
  constexpr int K = D_DIM, N = F_DIM;
  int g = blockIdx.x;
  int xcd = g & 7;
  int j = g >> 3;                 // 0..215
  int mt = xcd * 9 + (j % 9);     // 9 consecutive m-tiles per XCD
  int nt = j / 9;                 // 0..23
  if (mt >= meta[0]) return;
  int e = meta[1 + mt];
  int m0 = meta[1 + MAX_TILES + mt] * 128;
  int off = offs[e], cnt = offs[e + 1] - off;
  int n0 = nt * 128;

  __shared__ __align__(16) __hip_bfloat16 As[2 * 128 * 32];  // two BK=32 sub-tiles
  __shared__ __align__(16) __hip_bfloat16 Bs[2 * 128 * 32];

  int tid = threadIdx.x, lane = tid & 63, w = tid >> 6;
  int lr0 = w * 32 + (lane >> 2), lr1 = lr0 + 16;
  int ch = (lane & 3) ^ ((lane >> 3) & 3);  // source chunk for LDS position lane&3

  int r0 = m0 + lr0; if (r0 > cnt - 1) r0 = cnt - 1;
  int r1 = m0 + lr1; if (r1 > cnt - 1) r1 = cnt - 1;
  const __hip_bfloat16* a0 = A + (size_t)perm[off + r0] * K + ch * 8;
  const __hip_bfloat16* a1 = A + (size_t)perm[off + r1] * K + ch * 8;
  const __hip_bfloat16* Bbase = Bt + ((size_t)e * N + n0) * K;
  const __hip_bfloat16* bp0 = Bbase + (size_t)lr0 * K + ch * 8;
  const __hip_bfloat16* bp1 = Bbase + (size_t)lr1 * K + ch * 8;

  int wr = (w >> 1) * 64, wc = (w & 1) * 64;
  int mrow = lane & 15, cq = lane >> 4;
  int aoff[4], boff[4];
#pragma unroll
  for (int i = 0; i < 4; i++) {
    int rr = wr + i * 16 + mrow;
    aoff[i] = rr * 32 + ((cq ^ ((rr >> 1) & 3)) * 8);
    int rb = wc + i * 16 + mrow;
    boff[i] = rb * 32 + ((cq ^ ((rb >> 1) & 3)) * 8);
  }

  floatx4 acc[4][4];
#pragma unroll
  for (int i = 0; i < 4; i++)
#pragma unroll
    for (int jj = 0; jj < 4; jj++) acc[i][jj] = (floatx4){0.f, 0.f, 0.f, 0.f};

  for (int kk = 0; kk < K; kk += 64) {
    __syncthreads();
#pragma unroll
    for (int ks = 0; ks < 2; ks++) {
      int ko = kk + ks * 32;
      async16(a0 + ko, &As[ks * 4096 + (w * 32) * 32]);
      async16(a1 + ko, &As[ks * 4096 + (w * 32 + 16) * 32]);
      async16(bp0 + ko, &Bs[ks * 4096 + (w * 32) * 32]);
      async16(bp1 + ko, &Bs[ks * 4096 + (w * 32 + 16) * 32]);
    }
    __syncthreads();
#pragma unroll
    for (int ks = 0; ks < 2; ks++) {
      short8 af[4], bf[4];
#pragma unroll
      for (int i = 0; i < 4; i++) af[i] = *(const short8*)&As[ks * 4096 + aoff[i]];
#pragma unroll
      for (int i = 0; i < 4; i++) bf[i] = *(const short8*)&Bs[ks * 4096 + boff[i]];
#pragma unroll
      for (int mi = 0; mi < 4; mi++)
#pragma unroll
        for (int ni = 0; ni < 4; ni++)
          acc[mi][ni] = __builtin_amdgcn_mfma_f32_16x16x32_bf16(af[mi], bf[ni], acc[mi][ni], 0, 0, 0);
    }
  }

#pragma unroll
  for (int mi = 0; mi < 4; mi++) {
    int rowl = wr + mi * 16 + (lane >> 4) * 4;
#pragma unroll
    for (int ni = 0; ni < 4; ni++) {
      int col = n0 + wc + ni * 16 + (lane & 15);
      float bia = bias[(size_t)e * N + col];
#pragma unroll
      for (int r = 0; r < 4; r++) {
        int gm = m0 + rowl + r;
        if (gm < cnt)
          H[(size_t)(off + gm) * N + col] = __float2bfloat16(gelu_fast(acc[mi][ni][r] + bia));
      }
    }
  }
}

// ---------------- GEMM2: out[perm] = H @ w2t^T + b2, 128x64, BK=64 ----------
__global__ __launch_bounds__(256)
void moe_gemm2(const __hip_bfloat16* __restrict__ A,   // H [T][F] (permuted rows)
               const __hip_bfloat16* __restrict__ Bt,  // w2t [E][D][F]
               const float* __restrict__ bias,         // b2 [E][D]
               const int* __restrict__ meta,
               const int* __restrict__ offs,
               const int* __restrict__ perm,
               float* __restrict__ Out) {
  constexpr int K = F_DIM, N = D_DIM;
  int g = blockIdx.x;
  int xcd = g & 7;
  int j = g >> 3;                 // 0..107
  int mt = xcd * 9 + (j % 9);
  int nt = j / 9;                 // 0..11
  if (mt >= meta[0]) return;
  int e = meta[1 + mt];
  int m0 = meta[1 + MAX_TILES + mt] * 128;
  int off = offs[e], cnt = offs[e + 1] - off;
  int n0 = nt * 64;

  __shared__ __align__(16) __hip_bfloat16 As[2 * 128 * 32];
  __shared__ __align__(16) __hip_bfloat16 Bs[2 * 64 * 32];

  int tid = threadIdx.x, lane = tid & 63, w = tid >> 6;
  int lr0 = w * 32 + (lane >> 2), lr1 = lr0 + 16;
  int ch = (lane & 3) ^ ((lane >> 3) & 3);

  int r0 = m0 + lr0; if (r0 > cnt - 1) r0 = cnt - 1;
  int r1 = m0 + lr1; if (r1 > cnt - 1) r1 = cnt - 1;
  const __hip_bfloat16* a0 = A + (size_t)(off + r0) * K + ch * 8;
  const __hip_bfloat16* a1 = A + (size_t)(off + r1) * K + ch * 8;
  int br = w * 16 + (lane >> 2);  // wave w stages 16 B-rows per sub-tile
  const __hip_bfloat16* bp0 = Bt + ((size_t)e * N + n0 + br) * K + ch * 8;

  int mrow = lane & 15, cq = lane >> 4;
  int aoff[2], boff[4];
#pragma unroll
  for (int i = 0; i < 2; i++) {
    int rr = w * 32 + i * 16 + mrow;
    aoff[i] = rr * 32 + ((cq ^ ((rr >> 1) & 3)) * 8);
  }
#pragma unroll
  for (int i = 0; i < 4; i++) {
    int rb = i * 16 + mrow;
    boff[i] = rb * 32 + ((cq ^ ((rb >> 1) & 3)) * 8);
  }

  floatx4 acc[2][4];
#pragma unroll
  for (int i = 0; i < 2; i++)
#pragma unroll
    for (int jj = 0; jj < 4; jj++) acc[i][jj] = (floatx4){0.f, 0.f, 0.f, 0.f};

  for (int kk = 0; kk < K; kk += 64) {
    __syncthreads();
#pragma unroll
    for (int ks = 0; ks < 2; ks++) {
      int ko = kk + ks * 32;
      async16(a0 + ko, &As[ks * 4096 + (w * 32) * 32]);
      async16(a1 + ko, &As[ks * 4096 + (w * 32 + 16) * 32]);
      async16(bp0 + ko, &Bs[ks * 2048 + (w * 16) * 32]);
    }
    __syncthreads();
#pragma unroll
    for (int ks = 0; ks < 2; ks++) {
      short8 af[2], bf[4];
#pragma unroll
      for (int i = 0; i < 2; i++) af[i] = *(const short8*)&As[ks * 4096 + aoff[i]];
#pragma unroll
      for (int i = 0; i < 4; i++) bf[i] = *(const short8*)&Bs[ks * 2048 + boff[i]];
#pragma unroll
      for (int mi = 0; mi < 2; mi++)
#pragma unroll
        for (int ni = 0; ni < 4; ni++)
          acc[mi][ni] = __builtin_amdgcn_mfma_f32_16x16x32_bf16(af[mi], bf[ni], acc[mi][ni], 0, 0, 0);
    }
  }

#pragma unroll
  for (int mi = 0; mi < 2; mi++) {
    int rowl = w * 32 + mi * 16 + (lane >> 4) * 4;
#pragma unroll
    for (int ni = 0; ni < 4; ni++) {
      int col = n0 + ni * 16 + (lane & 15);
      float bia = bias[(size_t)e * N + col];
#pragma unroll
      for (int r = 0; r < 4; r++) {
        int gm = m0 + rowl + r;
        if (gm < cnt)
          Out[(size_t)perm[off + gm] * N + col] = acc[mi][ni][r] + bia;
      }
    }
  }
}

extern "C" void kernel_launch(void* const* d_in, const int* in_sizes, int n_in,
                              void* d_out, int out_size, void* d_ws, size_t ws_size,
                              hipStream_t stream) {
  const float* x  = (const float*)d_in[0];
  const float* gw = (const float*)d_in[1];
  const float* gb = (const float*)d_in[2];
  const float* w1 = (const float*)d_in[3];
  const float* b1 = (const float*)d_in[4];
  const float* w2 = (const float*)d_in[5];
  const float* b2 = (const float*)d_in[6];
  float* out = (float*)d_out;

  char* ws = (char*)d_ws;
  int* counts = (int*)(ws + 0);
  int* fill   = (int*)(ws + 32);
  int* offs   = (int*)(ws + 64);
  int* meta   = (int*)(ws + 128);   // 145 ints
  int* eidx   = (int*)(ws + 1024);
  int* perm   = (int*)(ws + 1024 + 4 * T_TOK);
  size_t off = 1024 + 8 * (size_t)T_TOK;
  __hip_bfloat16* xb  = (__hip_bfloat16*)(ws + off); off += (size_t)T_TOK * D_DIM * 2;
  __hip_bfloat16* w1t = (__hip_bfloat16*)(ws + off); off += (size_t)E_NUM * D_DIM * F_DIM * 2;
  __hip_bfloat16* w2t = (__hip_bfloat16*)(ws + off); off += (size_t)E_NUM * D_DIM * F_DIM * 2;
  __hip_bfloat16* H   = (__hip_bfloat16*)(ws + off); off += (size_t)T_TOK * F_DIM * 2;

  hipMemsetAsync(d_ws, 0, 64, stream);
  gate_kernel<<<T_TOK / 4, 256, 0, stream>>>(x, gw, gb, eidx, counts, xb);
  offsets_kernel<<<1, 64, 0, stream>>>(counts, offs, meta);
  scatter_kernel<<<T_TOK / 256, 256, 0, stream>>>(eidx, offs, fill, perm);
  transpose_bf16<<<dim3(F_DIM / 64, D_DIM / 64, E_NUM), 256, 0, stream>>>(w1, w1t, D_DIM, F_DIM);
  transpose_bf16<<<dim3(D_DIM / 64, F_DIM / 64, E_NUM), 256, 0, stream>>>(w2, w2t, F_DIM, D_DIM);
  moe_gemm1<<<8 * 9 * (F_DIM / 128), 256, 0, stream>>>(xb, w1t, b1, meta, offs, perm, H);
  moe_gemm2<<<8 * 9 * (D_DIM / 64), 256, 0, stream>>>(H, w2t, b2, meta, offs, perm, out);
}

// Round 4
// 385.588 us; speedup vs baseline: 2.1069x; 1.3130x over previous
//
#include <hip/hip_runtime.h>
#include <hip/hip_bf16.h>
#include <cstdint>
#include <cstddef>

static constexpr int T_TOK = 8192;   // B*S
static constexpr int D_DIM = 768;
static constexpr int E_NUM = 8;
static constexpr int F_DIM = 3072;
static constexpr int MAX_TILES = 72; // 8 XCD groups x 9 m-tiles; sum ceil(cnt/128) <= 71

typedef __attribute__((ext_vector_type(8))) short short8;
typedef __attribute__((ext_vector_type(4))) float floatx4;
typedef __attribute__((ext_vector_type(8))) unsigned short ushort8v;

__device__ __forceinline__ void async16(const void* g, void* l) {
  __builtin_amdgcn_global_load_lds(
      (const __attribute__((address_space(1))) unsigned int*)g,
      (__attribute__((address_space(3))) unsigned int*)l, 16, 0, 0);
}

// gelu tanh-approx in sigmoid form: x*sigmoid(1.59577x + 0.0713548x^3)
// max dev vs exact erf-gelu ~3e-4 (absmax headroom 4.8x)
__device__ __forceinline__ float gelu_fast(float v) {
  float s = v * (1.5957691f + 0.071354813f * v * v);
  return v / (1.0f + __expf(-s));
}

// ---------------- gate: logits fp32, argmax, fused x->bf16. NO atomics. ------
__global__ __launch_bounds__(256)
void gate_kernel(const float* __restrict__ x, const float* __restrict__ gw,
                 const float* __restrict__ gb, int* __restrict__ expert_idx,
                 __hip_bfloat16* __restrict__ xb) {
  int gid = blockIdx.x * blockDim.x + threadIdx.x;
  int tok = gid >> 6;
  int lane = threadIdx.x & 63;
  if (tok >= T_TOK) return;
  const float* xr = x + (size_t)tok * D_DIM;
  __hip_bfloat16* xbr = xb + (size_t)tok * D_DIM;
  float acc[8];
#pragma unroll
  for (int e = 0; e < 8; e++) acc[e] = 0.f;
#pragma unroll
  for (int i = 0; i < D_DIM / 64; i++) {
    int d = lane + i * 64;
    float v = xr[d];
    xbr[d] = __float2bfloat16(v);
    const float4* g4 = (const float4*)(gw + (size_t)d * 8);
    float4 a = g4[0], b = g4[1];
    acc[0] += v * a.x; acc[1] += v * a.y; acc[2] += v * a.z; acc[3] += v * a.w;
    acc[4] += v * b.x; acc[5] += v * b.y; acc[6] += v * b.z; acc[7] += v * b.w;
  }
#pragma unroll
  for (int e = 0; e < 8; e++) {
#pragma unroll
    for (int o = 32; o > 0; o >>= 1) acc[e] += __shfl_xor(acc[e], o, 64);
  }
  if (lane == 0) {
    int best = 0;
    float bv = acc[0] + gb[0];
#pragma unroll
    for (int e = 1; e < 8; e++) {
      float v = acc[e] + gb[e];
      if (v > bv) { bv = v; best = e; }  // strict > == np.argmax tie-break
    }
    expert_idx[tok] = best;
  }
}

// ---------------- count: LDS histogram, 8 global atomics per block ----------
__global__ __launch_bounds__(256)
void count_kernel(const int* __restrict__ expert_idx, int* __restrict__ counts) {
  __shared__ int h[E_NUM];
  if (threadIdx.x < E_NUM) h[threadIdx.x] = 0;
  __syncthreads();
  int t = blockIdx.x * blockDim.x + threadIdx.x;
  if (t < T_TOK) atomicAdd(&h[expert_idx[t]], 1);
  __syncthreads();
  if (threadIdx.x < E_NUM && h[threadIdx.x] > 0)
    atomicAdd(&counts[threadIdx.x], h[threadIdx.x]);
}

// ---------------- offsets + compact tile table ----------------
__global__ void offsets_kernel(const int* __restrict__ counts, int* __restrict__ offs,
                               int* __restrict__ meta) {
  if (threadIdx.x == 0) {
    int s = 0, tc = 0;
    for (int e = 0; e < E_NUM; e++) {
      offs[e] = s;
      int cnt = counts[e];
      for (int m = 0; m * 128 < cnt; m++) {
        meta[1 + tc] = e;
        meta[1 + MAX_TILES + tc] = m;
        tc++;
      }
      s += cnt;
    }
    offs[E_NUM] = s;
    meta[0] = tc;
  }
}

// ---------------- scatter: LDS ranks + block-aggregated global base --------
__global__ __launch_bounds__(256)
void scatter_kernel(const int* __restrict__ expert_idx, const int* __restrict__ offs,
                    int* __restrict__ fill, int* __restrict__ perm) {
  __shared__ int lcnt[E_NUM];
  __shared__ int lbase[E_NUM];
  if (threadIdx.x < E_NUM) lcnt[threadIdx.x] = 0;
  __syncthreads();
  int t = blockIdx.x * blockDim.x + threadIdx.x;
  int e = -1, rank = 0;
  if (t < T_TOK) {
    e = expert_idx[t];
    rank = atomicAdd(&lcnt[e], 1);   // LDS atomic: per-CU, cheap
  }
  __syncthreads();
  if (threadIdx.x < E_NUM)
    lbase[threadIdx.x] = (lcnt[threadIdx.x] > 0)
                           ? atomicAdd(&fill[threadIdx.x], lcnt[threadIdx.x]) : 0;
  __syncthreads();
  if (t < T_TOK) perm[offs[e] + lbase[e] + rank] = t;
}

// ---------------- weight transpose + cast: in [R][C] fp32 -> out [C][R] bf16 ----
__global__ __launch_bounds__(256)
void transpose_bf16(const float* __restrict__ in, __hip_bfloat16* __restrict__ out,
                    int R, int C) {
  __shared__ float t[64][65];
  const float* src = in + (size_t)blockIdx.z * R * C;
  __hip_bfloat16* dst = out + (size_t)blockIdx.z * R * C;
  int r0 = blockIdx.y * 64, c0 = blockIdx.x * 64;
  int tx = threadIdx.x & 15;
  int ty = threadIdx.x >> 4;
#pragma unroll
  for (int p = 0; p < 4; p++) {
    int r = ty + p * 16;
    float4 v = *(const float4*)&src[(size_t)(r0 + r) * C + c0 + tx * 4];
    t[tx * 4 + 0][r] = v.x; t[tx * 4 + 1][r] = v.y;
    t[tx * 4 + 2][r] = v.z; t[tx * 4 + 3][r] = v.w;
  }
  __syncthreads();
  int j = threadIdx.x & 7;
#pragma unroll
  for (int p = 0; p < 2; p++) {
    int cc = (threadIdx.x >> 3) + p * 32;
    __align__(16) __hip_bfloat16 tmp[8];
#pragma unroll
    for (int i = 0; i < 8; i++) tmp[i] = __float2bfloat16(t[cc][j * 8 + i]);
    *(ushort8v*)&dst[(size_t)(c0 + cc) * R + r0 + j * 8] = *(const ushort8v*)tmp;
  }
}

// ---------------- GEMM1: H[perm-order] = gelu(xb_gathered @ w1t^T + b1) ----------
// 128x128 tile, BK=64 (two swizzled BK=32 sub-tiles), XCD-grouped grid.
__global__ __launch_bounds__(256)
void moe_gemm1(const __hip_bfloat16* __restrict__ A,   // xb [T][D]
               const __hip_bfloat16* __restrict__ Bt,  // w1t [E][F][D]
               const float* __restrict__ bias,         // b1 [E][F]
               const int* __restrict__ meta,
               const int* __restrict__ offs,
               const int* __restrict__ perm,
               __hip_bfloat16* __restrict__ H) {
  constexpr int K = D_DIM, N = F_DIM;
  int g = blockIdx.x;
  int xcd = g & 7;
  int j = g >> 3;
  int mt = xcd * 9 + (j % 9);
  int nt = j / 9;
  if (mt >= meta[0]) return;
  int e = meta[1 + mt];
  int m0 = meta[1 + MAX_TILES + mt] * 128;
  int off = offs[e], cnt = offs[e + 1] - off;
  int n0 = nt * 128;

  __shared__ __align__(16) __hip_bfloat16 As[2 * 128 * 32];
  __shared__ __align__(16) __hip_bfloat16 Bs[2 * 128 * 32];

  int tid = threadIdx.x, lane = tid & 63, w = tid >> 6;
  int lr0 = w * 32 + (lane >> 2), lr1 = lr0 + 16;
  int ch = (lane & 3) ^ ((lane >> 3) & 3);

  int r0 = m0 + lr0; if (r0 > cnt - 1) r0 = cnt - 1;
  int r1 = m0 + lr1; if (r1 > cnt - 1) r1 = cnt - 1;
  const __hip_bfloat16* a0 = A + (size_t)perm[off + r0] * K + ch * 8;
  const __hip_bfloat16* a1 = A + (size_t)perm[off + r1] * K + ch * 8;
  const __hip_bfloat16* Bbase = Bt + ((size_t)e * N + n0) * K;
  const __hip_bfloat16* bp0 = Bbase + (size_t)lr0 * K + ch * 8;
  const __hip_bfloat16* bp1 = Bbase + (size_t)lr1 * K + ch * 8;

  int wr = (w >> 1) * 64, wc = (w & 1) * 64;
  int mrow = lane & 15, cq = lane >> 4;
  int aoff[4], boff[4];
#pragma unroll
  for (int i = 0; i < 4; i++) {
    int rr = wr + i * 16 + mrow;
    aoff[i] = rr * 32 + ((cq ^ ((rr >> 1) & 3)) * 8);
    int rb = wc + i * 16 + mrow;
    boff[i] = rb * 32 + ((cq ^ ((rb >> 1) & 3)) * 8);
  }

  floatx4 acc[4][4];
#pragma unroll
  for (int i = 0; i < 4; i++)
#pragma unroll
    for (int jj = 0; jj < 4; jj++) acc[i][jj] = (floatx4){0.f, 0.f, 0.f, 0.f};

  for (int kk = 0; kk < K; kk += 64) {
    __syncthreads();
#pragma unroll
    for (int ks = 0; ks < 2; ks++) {
      int ko = kk + ks * 32;
      async16(a0 + ko, &As[ks * 4096 + (w * 32) * 32]);
      async16(a1 + ko, &As[ks * 4096 + (w * 32 + 16) * 32]);
      async16(bp0 + ko, &Bs[ks * 4096 + (w * 32) * 32]);
      async16(bp1 + ko, &Bs[ks * 4096 + (w * 32 + 16) * 32]);
    }
    __syncthreads();
#pragma unroll
    for (int ks = 0; ks < 2; ks++) {
      short8 af[4], bf[4];
#pragma unroll
      for (int i = 0; i < 4; i++) af[i] = *(const short8*)&As[ks * 4096 + aoff[i]];
#pragma unroll
      for (int i = 0; i < 4; i++) bf[i] = *(const short8*)&Bs[ks * 4096 + boff[i]];
#pragma unroll
      for (int mi = 0; mi < 4; mi++)
#pragma unroll
        for (int ni = 0; ni < 4; ni++)
          acc[mi][ni] = __builtin_amdgcn_mfma_f32_16x16x32_bf16(af[mi], bf[ni], acc[mi][ni], 0, 0, 0);
    }
  }

#pragma unroll
  for (int mi = 0; mi < 4; mi++) {
    int rowl = wr + mi * 16 + (lane >> 4) * 4;
#pragma unroll
    for (int ni = 0; ni < 4; ni++) {
      int col = n0 + wc + ni * 16 + (lane & 15);
      float bia = bias[(size_t)e * N + col];
#pragma unroll
      for (int r = 0; r < 4; r++) {
        int gm = m0 + rowl + r;
        if (gm < cnt)
          H[(size_t)(off + gm) * N + col] = __float2bfloat16(gelu_fast(acc[mi][ni][r] + bia));
      }
    }
  }
}

// ---------------- GEMM2: out[perm] = H @ w2t^T + b2, 128x64, BK=64 ----------
__global__ __launch_bounds__(256)
void moe_gemm2(const __hip_bfloat16* __restrict__ A,   // H [T][F] (permuted rows)
               const __hip_bfloat16* __restrict__ Bt,  // w2t [E][D][F]
               const float* __restrict__ bias,         // b2 [E][D]
               const int* __restrict__ meta,
               const int* __restrict__ offs,
               const int* __restrict__ perm,
               float* __restrict__ Out) {
  constexpr int K = F_DIM, N = D_DIM;
  int g = blockIdx.x;
  int xcd = g & 7;
  int j = g >> 3;
  int mt = xcd * 9 + (j % 9);
  int nt = j / 9;
  if (mt >= meta[0]) return;
  int e = meta[1 + mt];
  int m0 = meta[1 + MAX_TILES + mt] * 128;
  int off = offs[e], cnt = offs[e + 1] - off;
  int n0 = nt * 64;

  __shared__ __align__(16) __hip_bfloat16 As[2 * 128 * 32];
  __shared__ __align__(16) __hip_bfloat16 Bs[2 * 64 * 32];

  int tid = threadIdx.x, lane = tid & 63, w = tid >> 6;
  int lr0 = w * 32 + (lane >> 2), lr1 = lr0 + 16;
  int ch = (lane & 3) ^ ((lane >> 3) & 3);

  int r0 = m0 + lr0; if (r0 > cnt - 1) r0 = cnt - 1;
  int r1 = m0 + lr1; if (r1 > cnt - 1) r1 = cnt - 1;
  const __hip_bfloat16* a0 = A + (size_t)(off + r0) * K + ch * 8;
  const __hip_bfloat16* a1 = A + (size_t)(off + r1) * K + ch * 8;
  int br = w * 16 + (lane >> 2);
  const __hip_bfloat16* bp0 = Bt + ((size_t)e * N + n0 + br) * K + ch * 8;

  int mrow = lane & 15, cq = lane >> 4;
  int aoff[2], boff[4];
#pragma unroll
  for (int i = 0; i < 2; i++) {
    int rr = w * 32 + i * 16 + mrow;
    aoff[i] = rr * 32 + ((cq ^ ((rr >> 1) & 3)) * 8);
  }
#pragma unroll
  for (int i = 0; i < 4; i++) {
    int rb = i * 16 + mrow;
    boff[i] = rb * 32 + ((cq ^ ((rb >> 1) & 3)) * 8);
  }

  floatx4 acc[2][4];
#pragma unroll
  for (int i = 0; i < 2; i++)
#pragma unroll
    for (int jj = 0; jj < 4; jj++) acc[i][jj] = (floatx4){0.f, 0.f, 0.f, 0.f};

  for (int kk = 0; kk < K; kk += 64) {
    __syncthreads();
#pragma unroll
    for (int ks = 0; ks < 2; ks++) {
      int ko = kk + ks * 32;
      async16(a0 + ko, &As[ks * 4096 + (w * 32) * 32]);
      async16(a1 + ko, &As[ks * 4096 + (w * 32 + 16) * 32]);
      async16(bp0 + ko, &Bs[ks * 2048 + (w * 16) * 32]);
    }
    __syncthreads();
#pragma unroll
    for (int ks = 0; ks < 2; ks++) {
      short8 af[2], bf[4];
#pragma unroll
      for (int i = 0; i < 2; i++) af[i] = *(const short8*)&As[ks * 4096 + aoff[i]];
#pragma unroll
      for (int i = 0; i < 4; i++) bf[i] = *(const short8*)&Bs[ks * 2048 + boff[i]];
#pragma unroll
      for (int mi = 0; mi < 2; mi++)
#pragma unroll
        for (int ni = 0; ni < 4; ni++)
          acc[mi][ni] = __builtin_amdgcn_mfma_f32_16x16x32_bf16(af[mi], bf[ni], acc[mi][ni], 0, 0, 0);
    }
  }

#pragma unroll
  for (int mi = 0; mi < 2; mi++) {
    int rowl = w * 32 + mi * 16 + (lane >> 4) * 4;
#pragma unroll
    for (int ni = 0; ni < 4; ni++) {
      int col = n0 + ni * 16 + (lane & 15);
      float bia = bias[(size_t)e * N + col];
#pragma unroll
      for (int r = 0; r < 4; r++) {
        int gm = m0 + rowl + r;
        if (gm < cnt)
          Out[(size_t)perm[off + gm] * N + col] = acc[mi][ni][r] + bia;
      }
    }
  }
}

extern "C" void kernel_launch(void* const* d_in, const int* in_sizes, int n_in,
                              void* d_out, int out_size, void* d_ws, size_t ws_size,
                              hipStream_t stream) {
  const float* x  = (const float*)d_in[0];
  const float* gw = (const float*)d_in[1];
  const float* gb = (const float*)d_in[2];
  const float* w1 = (const float*)d_in[3];
  const float* b1 = (const float*)d_in[4];
  const float* w2 = (const float*)d_in[5];
  const float* b2 = (const float*)d_in[6];
  float* out = (float*)d_out;

  char* ws = (char*)d_ws;
  int* counts = (int*)(ws + 0);
  int* fill   = (int*)(ws + 32);
  int* offs   = (int*)(ws + 64);
  int* meta   = (int*)(ws + 128);   // 145 ints
  int* eidx   = (int*)(ws + 1024);
  int* perm   = (int*)(ws + 1024 + 4 * T_TOK);
  size_t off = 1024 + 8 * (size_t)T_TOK;
  __hip_bfloat16* xb  = (__hip_bfloat16*)(ws + off); off += (size_t)T_TOK * D_DIM * 2;
  __hip_bfloat16* w1t = (__hip_bfloat16*)(ws + off); off += (size_t)E_NUM * D_DIM * F_DIM * 2;
  __hip_bfloat16* w2t = (__hip_bfloat16*)(ws + off); off += (size_t)E_NUM * D_DIM * F_DIM * 2;
  __hip_bfloat16* H   = (__hip_bfloat16*)(ws + off); off += (size_t)T_TOK * F_DIM * 2;

  hipMemsetAsync(d_ws, 0, 64, stream);  // counts + fill
  gate_kernel<<<T_TOK / 4, 256, 0, stream>>>(x, gw, gb, eidx, xb);
  count_kernel<<<T_TOK / 256, 256, 0, stream>>>(eidx, counts);
  offsets_kernel<<<1, 64, 0, stream>>>(counts, offs, meta);
  scatter_kernel<<<T_TOK / 256, 256, 0, stream>>>(eidx, offs, fill, perm);
  transpose_bf16<<<dim3(F_DIM / 64, D_DIM / 64, E_NUM), 256, 0, stream>>>(w1, w1t, D_DIM, F_DIM);
  transpose_bf16<<<dim3(D_DIM / 64, F_DIM / 64, E_NUM), 256, 0, stream>>>(w2, w2t, F_DIM, D_DIM);
  moe_gemm1<<<8 * 9 * (F_DIM / 128), 256, 0, stream>>>(xb, w1t, b1, meta, offs, perm, H);
  moe_gemm2<<<8 * 9 * (D_DIM / 64), 256, 0, stream>>>(H, w2t, b2, meta, offs, perm, out);
}